// Round 1
// baseline (410.516 us; speedup 1.0000x reference)
//
#include <hip/hip_runtime.h>

typedef unsigned short u16;
typedef __attribute__((ext_vector_type(8))) short bf16x8;
typedef __attribute__((ext_vector_type(4))) float f32x4;

__device__ __forceinline__ u16 f2bf(float f) {
    union { float f; unsigned u; } v; v.f = f;
    unsigned r = v.u + 0x7fffu + ((v.u >> 16) & 1u);
    return (u16)(r >> 16);
}

__device__ __forceinline__ void gload16(const void* g, void* l) {
    __builtin_amdgcn_global_load_lds((const __attribute__((address_space(1))) void*)g,
                                     (__attribute__((address_space(3))) void*)l, 16, 0, 0);
}

// ---------------- fp32 -> bf16 convert (8 elems/thread) ----------------
__global__ void cvt_f32_bf16(const float* __restrict__ in, u16* __restrict__ out, int n) {
    int base = (blockIdx.x * blockDim.x + threadIdx.x) * 8;
    if (base >= n) return;
    float4 a = *reinterpret_cast<const float4*>(in + base);
    float4 b = *reinterpret_cast<const float4*>(in + base + 4);
    u16 o[8] = { f2bf(a.x), f2bf(a.y), f2bf(a.z), f2bf(a.w),
                 f2bf(b.x), f2bf(b.y), f2bf(b.z), f2bf(b.w) };
    *reinterpret_cast<bf16x8*>(out + base) = *reinterpret_cast<const bf16x8*>(o);
}

// ---------------- C[M][N] = A[M][K] * B[N][K]^T  (bf16 in, f32 acc) ----------------
// m97 structure: 128x128 tile, BK=32, 4 waves, global_load_lds width 16.
template<int OUT_BF16>
__global__ void gemm_bt(const u16* __restrict__ A, const u16* __restrict__ B,
                        void* __restrict__ Cout, int M, int N, int K) {
    __shared__ u16 As[128 * 32];
    __shared__ u16 Bs[128 * 32];
    const int tid  = threadIdx.x;
    const int lane = tid & 63;
    const int w    = tid >> 6;          // 0..3
    const int wr   = (w >> 1) * 64;     // wave quadrant
    const int wc   = (w & 1) * 64;
    const int nbm  = M >> 7;
    const int bm   = (blockIdx.x % nbm) << 7;
    const int bn   = (blockIdx.x / nbm) << 7;

    f32x4 acc[4][4] = {};

    // staging: wave w owns chunks 2w,2w+1 (each 1024B = 16 rows x 32 cols)
    const int  c0   = w * 2;
    const long arow = (long)(bm + c0 * 16 + (lane >> 2)) * K + (lane & 3) * 8;
    const long brow = (long)(bn + c0 * 16 + (lane >> 2)) * K + (lane & 3) * 8;
    u16* as0 = &As[c0 * 512];
    u16* bs0 = &Bs[c0 * 512];

    for (int k0 = 0; k0 < K; k0 += 32) {
        __syncthreads();
        gload16(A + arow + k0,           as0);
        gload16(A + arow + 16 * K + k0,  as0 + 512);
        gload16(B + brow + k0,           bs0);
        gload16(B + brow + 16 * K + k0,  bs0 + 512);
        __syncthreads();
        bf16x8 a[4], b[4];
#pragma unroll
        for (int m = 0; m < 4; ++m)
            a[m] = *reinterpret_cast<const bf16x8*>(&As[(wr + m * 16 + (lane & 15)) * 32 + (lane >> 4) * 8]);
#pragma unroll
        for (int n = 0; n < 4; ++n)
            b[n] = *reinterpret_cast<const bf16x8*>(&Bs[(wc + n * 16 + (lane & 15)) * 32 + (lane >> 4) * 8]);
#pragma unroll
        for (int m = 0; m < 4; ++m)
#pragma unroll
            for (int n = 0; n < 4; ++n)
                acc[m][n] = __builtin_amdgcn_mfma_f32_16x16x32_bf16(a[m], b[n], acc[m][n], 0, 0, 0);
    }

    const int r0 = (lane >> 4) * 4;
    const int cc = lane & 15;
#pragma unroll
    for (int m = 0; m < 4; ++m)
#pragma unroll
        for (int n = 0; n < 4; ++n) {
            long row = bm + wr + m * 16 + r0;
            long col = bn + wc + n * 16 + cc;
            if (OUT_BF16) {
                u16* C = (u16*)Cout;
#pragma unroll
                for (int j = 0; j < 4; ++j) C[(row + j) * N + col] = f2bf(acc[m][n][j]);
            } else {
                float* C = (float*)Cout;
#pragma unroll
                for (int j = 0; j < 4; ++j) C[(row + j) * N + col] = acc[m][n][j];
            }
        }
}

// ---------------- causal flash attention ----------------
// grid (32 qblocks, 64 bh), 256 thr. QBLK=64 (16 rows/wave), KVBLK=64, D=64.
// qkv layout: [b*2048+t][3072], q at +0, k at +1024, v at +2048, head h at h*64.
__global__ void attn_fwd(const u16* __restrict__ qkv, u16* __restrict__ out) {
    const int qb   = blockIdx.x;
    const int bh   = blockIdx.y;
    const int b    = bh >> 4;
    const int h    = bh & 15;
    const int tid  = threadIdx.x;
    const int lane = tid & 63;
    const int w    = tid >> 6;
    const int q0   = qb * 64;

    __shared__ u16 Ks[64 * 64];    // XOR-swizzled slots
    __shared__ u16 Vt[64][72];     // transposed V, pad 72
    __shared__ u16 Pl[64][72];     // P tile, pad 72

    // Q fragments in registers (reused across all KV tiles)
    bf16x8 aq[2];
    {
        const long qoff = (long)(b * 2048 + q0 + w * 16 + (lane & 15)) * 3072 + h * 64 + (lane >> 4) * 8;
        aq[0] = *reinterpret_cast<const bf16x8*>(qkv + qoff);
        aq[1] = *reinterpret_cast<const bf16x8*>(qkv + qoff + 32);
    }

    f32x4 acc[4] = {};
    float m_r[4] = { -3e38f, -3e38f, -3e38f, -3e38f };
    float l_r[4] = {};

    // K staging source mapping (pre-swizzled global source, linear LDS dest)
    const int kc0   = w * 2;
    const int krow0 = kc0 * 8 + (lane >> 3);
    const int kslot = (lane & 7) ^ (krow0 & 7);  // same for row0+8

    const int nt = qb + 1;
    for (int t = 0; t < nt; ++t) {
        const int kv0 = t * 64;
        __syncthreads();
        {   // K tile: 2 chunks/wave via global_load_lds
            const u16* ksrc = qkv + (long)(b * 2048 + kv0 + krow0) * 3072 + 1024 + h * 64 + kslot * 8;
            gload16(ksrc,                 &Ks[kc0 * 512]);
            gload16(ksrc + (long)8 * 3072, &Ks[kc0 * 512 + 512]);
        }
        {   // V tile transposed: lane = kv row, wave w covers d = w*16..w*16+15
            const u16* vsrc = qkv + (long)(b * 2048 + kv0 + lane) * 3072 + 2048 + h * 64 + w * 16;
            bf16x8 v0 = *reinterpret_cast<const bf16x8*>(vsrc);
            bf16x8 v1 = *reinterpret_cast<const bf16x8*>(vsrc + 8);
#pragma unroll
            for (int i = 0; i < 8; ++i) Vt[w * 16 + i][lane]     = (u16)v0[i];
#pragma unroll
            for (int i = 0; i < 8; ++i) Vt[w * 16 + 8 + i][lane] = (u16)v1[i];
        }
        __syncthreads();

        // S = Q K^T  (16 q-rows x 64 kv)
        f32x4 s[4];
#pragma unroll
        for (int n = 0; n < 4; ++n) {
            f32x4 z = {};
#pragma unroll
            for (int ks = 0; ks < 2; ++ks) {
                int r    = n * 16 + (lane & 15);
                int slot = ((lane >> 4) + 4 * ks) ^ (r & 7);
                bf16x8 bk = *reinterpret_cast<const bf16x8*>(&Ks[r * 64 + slot * 8]);
                z = __builtin_amdgcn_mfma_f32_16x16x32_bf16(aq[ks], bk, z, 0, 0, 0);
            }
            s[n] = z;
        }

        // scale + causal mask + row max
        float rmax[4] = { -3e38f, -3e38f, -3e38f, -3e38f };
        const int kvc = kv0 + (lane & 15);
        const int qg  = q0 + w * 16 + (lane >> 4) * 4;
#pragma unroll
        for (int n = 0; n < 4; ++n)
#pragma unroll
            for (int j = 0; j < 4; ++j) {
                float v = s[n][j] * 0.125f;
                v = (kvc + n * 16 <= qg + j) ? v : -3e38f;
                s[n][j] = v;
                rmax[j] = fmaxf(rmax[j], v);
            }
#pragma unroll
        for (int off = 1; off < 16; off <<= 1)
#pragma unroll
            for (int j = 0; j < 4; ++j)
                rmax[j] = fmaxf(rmax[j], __shfl_xor(rmax[j], off));

        float alpha[4], rsum[4] = {};
#pragma unroll
        for (int j = 0; j < 4; ++j) {
            float mn = fmaxf(m_r[j], rmax[j]);
            alpha[j] = __expf(m_r[j] - mn);
            m_r[j]   = mn;
        }
#pragma unroll
        for (int n = 0; n < 4; ++n)
#pragma unroll
            for (int j = 0; j < 4; ++j) {
                float p = __expf(s[n][j] - m_r[j]);
                s[n][j] = p;
                rsum[j] += p;
            }
#pragma unroll
        for (int off = 1; off < 16; off <<= 1)
#pragma unroll
            for (int j = 0; j < 4; ++j) rsum[j] += __shfl_xor(rsum[j], off);
#pragma unroll
        for (int j = 0; j < 4; ++j) l_r[j] = l_r[j] * alpha[j] + rsum[j];
#pragma unroll
        for (int f = 0; f < 4; ++f)
#pragma unroll
            for (int j = 0; j < 4; ++j) acc[f][j] *= alpha[j];

        // P -> LDS (bf16), wave-local rows
#pragma unroll
        for (int n = 0; n < 4; ++n)
#pragma unroll
            for (int j = 0; j < 4; ++j)
                Pl[w * 16 + (lane >> 4) * 4 + j][n * 16 + (lane & 15)] = f2bf(s[n][j]);

        // O += P V
#pragma unroll
        for (int f = 0; f < 4; ++f)
#pragma unroll
            for (int ks = 0; ks < 2; ++ks) {
                bf16x8 ap = *reinterpret_cast<const bf16x8*>(&Pl[w * 16 + (lane & 15)][(lane >> 4) * 8 + ks * 32]);
                bf16x8 bv = *reinterpret_cast<const bf16x8*>(&Vt[f * 16 + (lane & 15)][(lane >> 4) * 8 + ks * 32]);
                acc[f] = __builtin_amdgcn_mfma_f32_16x16x32_bf16(ap, bv, acc[f], 0, 0, 0);
            }
    }

    // epilogue: out[t][h*64+d] bf16
#pragma unroll
    for (int f = 0; f < 4; ++f)
#pragma unroll
        for (int j = 0; j < 4; ++j) {
            int qrow = q0 + w * 16 + (lane >> 4) * 4 + j;
            float o  = acc[f][j] / l_r[j];
            out[(long)(b * 2048 + qrow) * 1024 + h * 64 + f * 16 + (lane & 15)] = f2bf(o);
        }
}

extern "C" void kernel_launch(void* const* d_in, const int* in_sizes, int n_in,
                              void* d_out, int out_size, void* d_ws, size_t ws_size,
                              hipStream_t stream) {
    const float* x     = (const float*)d_in[0];
    const float* w_qkv = (const float*)d_in[1];
    const float* w_out = (const float*)d_in[2];
    float* out = (float*)d_out;

    char* ws = (char*)d_ws;
    u16* x_bf    = (u16*)(ws);                         // 16 MB
    u16* wqkv_bf = (u16*)(ws + (16u << 20));           // 6 MB
    u16* wout_bf = (u16*)(ws + (22u << 20));           // 2 MB
    u16* qkv_bf  = (u16*)(ws + (24u << 20));           // 48 MB
    u16* attn_bf = (u16*)(ws + (72u << 20));           // 16 MB  (total 88 MB)

    const int nx = 8192 * 1024, nq = 3072 * 1024, no = 1024 * 1024;
    cvt_f32_bf16<<<nx / 8 / 256, 256, 0, stream>>>(x,     x_bf,    nx);
    cvt_f32_bf16<<<nq / 8 / 256, 256, 0, stream>>>(w_qkv, wqkv_bf, nq);
    cvt_f32_bf16<<<no / 8 / 256, 256, 0, stream>>>(w_out, wout_bf, no);

    // qkv = x @ w_qkv^T   (8192 x 3072 x K=1024)
    gemm_bt<1><<<dim3(64 * 24), 256, 0, stream>>>(x_bf, wqkv_bf, qkv_bf, 8192, 3072, 1024);

    // causal flash attention
    attn_fwd<<<dim3(32, 64), 256, 0, stream>>>(qkv_bf, attn_bf);

    // out = attn @ w_out^T (8192 x 1024 x K=1024), fp32 epilogue
    gemm_bt<0><<<dim3(64 * 8), 256, 0, stream>>>(attn_bf, wout_bf, out, 8192, 1024, 1024);
}

// Round 2
// 245.464 us; speedup vs baseline: 1.6724x; 1.6724x over previous
//
#include <hip/hip_runtime.h>

typedef unsigned short u16;
typedef __attribute__((ext_vector_type(8))) short bf16x8;
typedef __attribute__((ext_vector_type(4))) float f32x4;
typedef __attribute__((ext_vector_type(16))) float f32x16;

__device__ __forceinline__ u16 f2bf(float f) {
    union { float f; unsigned u; } v; v.f = f;
    unsigned r = v.u + 0x7fffu + ((v.u >> 16) & 1u);
    return (u16)(r >> 16);
}

__device__ __forceinline__ void gload16(const void* g, void* l) {
    __builtin_amdgcn_global_load_lds((const __attribute__((address_space(1))) void*)g,
                                     (__attribute__((address_space(3))) void*)l, 16, 0, 0);
}

__device__ __forceinline__ float exp2_fast(float x) {
    float r; asm("v_exp_f32 %0, %1" : "=v"(r) : "v"(x)); return r;
}
__device__ __forceinline__ unsigned cvtpk(float lo, float hi) {
    unsigned r; asm("v_cvt_pk_bf16_f32 %0, %1, %2" : "=v"(r) : "v"(lo), "v"(hi)); return r;
}
__device__ __forceinline__ void permswap(unsigned& a, unsigned& b) {
    asm("v_permlane32_swap_b32 %0, %1" : "+v"(a), "+v"(b));
}
__device__ __forceinline__ f32x16 mfma32(bf16x8 a, bf16x8 b, f32x16 c) {
    return __builtin_amdgcn_mfma_f32_32x32x16_bf16(a, b, c, 0, 0, 0);
}

// ---------------- fp32 -> bf16 convert (8 elems/thread) ----------------
__global__ void cvt_f32_bf16(const float* __restrict__ in, u16* __restrict__ out, int n) {
    int base = (blockIdx.x * blockDim.x + threadIdx.x) * 8;
    if (base >= n) return;
    float4 a = *reinterpret_cast<const float4*>(in + base);
    float4 b = *reinterpret_cast<const float4*>(in + base + 4);
    u16 o[8] = { f2bf(a.x), f2bf(a.y), f2bf(a.z), f2bf(a.w),
                 f2bf(b.x), f2bf(b.y), f2bf(b.z), f2bf(b.w) };
    *reinterpret_cast<bf16x8*>(out + base) = *reinterpret_cast<const bf16x8*>(o);
}

// ---------------- C[M][N] = A[M][K] * B[N][K]^T  (bf16 in, f32 acc) ----------------
template<int OUT_BF16>
__global__ void gemm_bt(const u16* __restrict__ A, const u16* __restrict__ B,
                        void* __restrict__ Cout, int M, int N, int K) {
    __shared__ u16 As[128 * 32];
    __shared__ u16 Bs[128 * 32];
    const int tid  = threadIdx.x;
    const int lane = tid & 63;
    const int w    = tid >> 6;
    const int wr   = (w >> 1) * 64;
    const int wc   = (w & 1) * 64;
    const int nbm  = M >> 7;
    const int bm   = (blockIdx.x % nbm) << 7;
    const int bn   = (blockIdx.x / nbm) << 7;

    f32x4 acc[4][4] = {};

    const int  c0   = w * 2;
    const long arow = (long)(bm + c0 * 16 + (lane >> 2)) * K + (lane & 3) * 8;
    const long brow = (long)(bn + c0 * 16 + (lane >> 2)) * K + (lane & 3) * 8;
    u16* as0 = &As[c0 * 512];
    u16* bs0 = &Bs[c0 * 512];

    for (int k0 = 0; k0 < K; k0 += 32) {
        __syncthreads();
        gload16(A + arow + k0,           as0);
        gload16(A + arow + 16 * K + k0,  as0 + 512);
        gload16(B + brow + k0,           bs0);
        gload16(B + brow + 16 * K + k0,  bs0 + 512);
        __syncthreads();
        bf16x8 a[4], b[4];
#pragma unroll
        for (int m = 0; m < 4; ++m)
            a[m] = *reinterpret_cast<const bf16x8*>(&As[(wr + m * 16 + (lane & 15)) * 32 + (lane >> 4) * 8]);
#pragma unroll
        for (int n = 0; n < 4; ++n)
            b[n] = *reinterpret_cast<const bf16x8*>(&Bs[(wc + n * 16 + (lane & 15)) * 32 + (lane >> 4) * 8]);
#pragma unroll
        for (int m = 0; m < 4; ++m)
#pragma unroll
            for (int n = 0; n < 4; ++n)
                acc[m][n] = __builtin_amdgcn_mfma_f32_16x16x32_bf16(a[m], b[n], acc[m][n], 0, 0, 0);
    }

    const int r0 = (lane >> 4) * 4;
    const int cc = lane & 15;
#pragma unroll
    for (int m = 0; m < 4; ++m)
#pragma unroll
        for (int n = 0; n < 4; ++n) {
            long row = bm + wr + m * 16 + r0;
            long col = bn + wc + n * 16 + cc;
            if (OUT_BF16) {
                u16* C = (u16*)Cout;
#pragma unroll
                for (int j = 0; j < 4; ++j) C[(row + j) * N + col] = f2bf(acc[m][n][j]);
            } else {
                float* C = (float*)Cout;
#pragma unroll
                for (int j = 0; j < 4; ++j) C[(row + j) * N + col] = acc[m][n][j];
            }
        }
}

// ---------------- causal flash attention, swapped-operand 32x32 ----------------
// grid (64 bh, 16 qbi), 256 thr. Block QBLK=128 (32 q-rows/wave), KVBLK=64, D=64.
// Swapped frame: S^T = mfma(K, Q), O^T = mfma(V^T, P); q = lane&31 throughout.
template<int RB>
__device__ __forceinline__ bf16x8 pack8(const f32x16& S) {
    unsigned A0 = cvtpk(S[RB + 0], S[RB + 1]);
    unsigned A1 = cvtpk(S[RB + 2], S[RB + 3]);
    unsigned B0 = cvtpk(S[RB + 4], S[RB + 5]);
    unsigned B1 = cvtpk(S[RB + 6], S[RB + 7]);
    permswap(A0, B0);
    permswap(A1, B1);
    union { unsigned u[4]; bf16x8 v; } pk;
    pk.u[0] = A0; pk.u[1] = A1; pk.u[2] = B0; pk.u[3] = B1;
    return pk.v;
}

__global__ __launch_bounds__(256, 4)
void attn_fwd(const u16* __restrict__ qkv, u16* __restrict__ out) {
    const int bh  = blockIdx.x;
    const int b   = bh >> 4, h = bh & 15;
    const int qb  = 15 - (int)blockIdx.y;       // biggest blocks dispatch first
    const int tid = threadIdx.x;
    const int lane = tid & 63;
    const int w    = tid >> 6;
    const int l31  = lane & 31;
    const int hi   = lane >> 5;
    const int qw0  = qb * 128 + w * 32;

    __shared__ u16 Ks[64 * 64];   // [kv][e-slot swizzled]: byte = kv*128 + ((slot^(kv&7))<<4)
    __shared__ u16 Vt[64 * 64];   // [d][kv-slot swizzled]

    // Q fragments: Q[q=qw0+l31][e = c*16 + hi*8 + j]
    bf16x8 aq[4];
    {
        const u16* qp = qkv + (long)(b * 2048 + qw0 + l31) * 3072 + h * 64 + hi * 8;
#pragma unroll
        for (int c = 0; c < 4; ++c) aq[c] = *(const bf16x8*)(qp + c * 16);
    }

    f32x16 o0 = {}, o1 = {};
    float m_r = -3e38f, l_r = 0.f;
    const float K2 = 0.18033688011112042f;  // (1/8)*log2(e)

    // K staging: pre-swizzled global source, linear LDS dest (G21)
    const int krow  = w * 16 + (lane >> 3);
    const int kslot = (lane & 7) ^ (lane >> 3);
    const u16* ksrc0 = qkv + (long)(b * 2048 + krow) * 3072 + 1024 + h * 64 + kslot * 8;
    // V staging: lane = kv row; wave w covers d = w*16 .. w*16+15
    const u16* vsrc0 = qkv + (long)(b * 2048 + lane) * 3072 + 2048 + h * 64 + w * 16;

    const int nt = 2 * (qb + 1);
    for (int t = 0; t < nt; ++t) {
        const long kvoff = (long)t * 64 * 3072;
        __syncthreads();
        gload16(ksrc0 + kvoff,                  &Ks[w * 1024]);
        gload16(ksrc0 + kvoff + (long)8 * 3072, &Ks[w * 1024 + 512]);
        {
            bf16x8 v0 = *(const bf16x8*)(vsrc0 + kvoff);
            bf16x8 v1 = *(const bf16x8*)(vsrc0 + kvoff + 8);
#pragma unroll
            for (int i = 0; i < 8; ++i) {
                int d0 = w * 16 + i, d1 = d0 + 8;
                Vt[d0 * 64 + ((((lane >> 3) ^ d0) & 7) << 3) + (lane & 7)] = (u16)v0[i];
                Vt[d1 * 64 + ((((lane >> 3) ^ d1) & 7) << 3) + (lane & 7)] = (u16)v1[i];
            }
        }
        __syncthreads();

        const int kv0 = t * 64;
        if (kv0 > qw0 + 31) continue;    // fully masked for this wave

        // ---- S^T = K · Q^T (two 32-kv subtiles) ----
        f32x16 s0 = {}, s1 = {};
#pragma unroll
        for (int c = 0; c < 4; ++c) {
            const int sl = 2 * c + hi;
            bf16x8 k0 = *(const bf16x8*)&Ks[l31 * 64        + ((sl ^ (l31 & 7)) << 3)];
            bf16x8 k1 = *(const bf16x8*)&Ks[(l31 + 32) * 64 + ((sl ^ (l31 & 7)) << 3)];
            s0 = mfma32(k0, aq[c], s0);
            s1 = mfma32(k1, aq[c], s1);
        }

        // ---- causal mask (diagonal tiles only) ----
        if (kv0 + 63 > qw0) {
            const int qrel = qw0 + l31 - kv0;
#pragma unroll
            for (int r = 0; r < 16; ++r) {
                const int kl = (r & 3) + 8 * (r >> 2) + 4 * hi;
                if (kl > qrel)      s0[r] = -3e38f;
                if (kl + 32 > qrel) s1[r] = -3e38f;
            }
        }

        // ---- online softmax (in-register; q = lane&31) ----
        float mx = m_r;
#pragma unroll
        for (int r = 0; r < 16; ++r) mx = fmaxf(mx, fmaxf(s0[r], s1[r]));
        mx = fmaxf(mx, __shfl_xor(mx, 32));

        const float alpha = exp2_fast((m_r - mx) * K2);
        const float mk = mx * K2;
        float sum = 0.f;
#pragma unroll
        for (int r = 0; r < 16; ++r) {
            float p0 = exp2_fast(fmaf(s0[r], K2, -mk));
            float p1 = exp2_fast(fmaf(s1[r], K2, -mk));
            s0[r] = p0; s1[r] = p1;
            sum += p0 + p1;
        }
        sum += __shfl_xor(sum, 32);
        l_r = l_r * alpha + sum;
        m_r = mx;
#pragma unroll
        for (int r = 0; r < 16; ++r) { o0[r] *= alpha; o1[r] *= alpha; }

        // ---- P -> bf16 A/B-frag words (cvt_pk + permlane32_swap, T12) ----
        bf16x8 pw[4];
        pw[0] = pack8<0>(s0); pw[1] = pack8<8>(s0);
        pw[2] = pack8<0>(s1); pw[3] = pack8<8>(s1);

        // ---- O^T += V^T · P^T ----
#pragma unroll
        for (int c = 0; c < 4; ++c) {
            const int sl = 2 * c + hi;
            bf16x8 v0 = *(const bf16x8*)&Vt[l31 * 64        + ((sl ^ (l31 & 7)) << 3)];
            bf16x8 v1 = *(const bf16x8*)&Vt[(l31 + 32) * 64 + ((sl ^ (l31 & 7)) << 3)];
            o0 = mfma32(v0, pw[c], o0);
            o1 = mfma32(v1, pw[c], o1);
        }
    }

    // ---- epilogue: out[q][h*64+d] = O^T[d][q] / l ----
    const float rl = 1.0f / l_r;
    u16* op = out + (long)(b * 2048 + qw0 + l31) * 1024 + h * 64;
#pragma unroll
    for (int r = 0; r < 16; ++r) {
        const int d = (r & 3) + 8 * (r >> 2) + 4 * hi;
        op[d]      = f2bf(o0[r] * rl);
        op[d + 32] = f2bf(o1[r] * rl);
    }
}

extern "C" void kernel_launch(void* const* d_in, const int* in_sizes, int n_in,
                              void* d_out, int out_size, void* d_ws, size_t ws_size,
                              hipStream_t stream) {
    const float* x     = (const float*)d_in[0];
    const float* w_qkv = (const float*)d_in[1];
    const float* w_out = (const float*)d_in[2];
    float* out = (float*)d_out;

    char* ws = (char*)d_ws;
    u16* x_bf    = (u16*)(ws);
    u16* wqkv_bf = (u16*)(ws + (16u << 20));
    u16* wout_bf = (u16*)(ws + (22u << 20));
    u16* qkv_bf  = (u16*)(ws + (24u << 20));
    u16* attn_bf = (u16*)(ws + (72u << 20));

    const int nx = 8192 * 1024, nq = 3072 * 1024, no = 1024 * 1024;
    cvt_f32_bf16<<<nx / 8 / 256, 256, 0, stream>>>(x,     x_bf,    nx);
    cvt_f32_bf16<<<nq / 8 / 256, 256, 0, stream>>>(w_qkv, wqkv_bf, nq);
    cvt_f32_bf16<<<no / 8 / 256, 256, 0, stream>>>(w_out, wout_bf, no);

    gemm_bt<1><<<dim3(64 * 24), 256, 0, stream>>>(x_bf, wqkv_bf, qkv_bf, 8192, 3072, 1024);

    attn_fwd<<<dim3(64, 16), 256, 0, stream>>>(qkv_bf, attn_bf);

    gemm_bt<0><<<dim3(64 * 8), 256, 0, stream>>>(attn_bf, wout_bf, out, 8192, 1024, 1024);
}